// Round 6
// baseline (2041.564 us; speedup 1.0000x reference)
//
#include <hip/hip_runtime.h>

// stackCLSTM: T=32, B=128, I=64, H=128, E=4, N_TRAP=100
// ws layout (float-word offsets):
//   W_all  [64][3072] fp32        @ 0         (196608)
//   bias   [3072] fp32            @ 196608    (3072)
//   WhhP   [kq][ii][cc][c2] u32   @ 199680    (131072)  fp16-pair packed Whh h-part
//   WgP    [e][kq][g][ii][cc][p2] @ 330752    (163840)  fp16-pair packed gate h-part
//   XG     [4096][3072] fp32      @ 494592    (12582912)
//   Gst    [4][4096*512] fp32     @ 13077504  (8388608)
#define OFF_WALL   0
#define OFF_BIAS   196608
#define OFF_WHHH   199680
#define OFF_WGH    330752
#define OFF_XG     494592
#define OFF_GST    13077504
#define GST_PLANE  2097152

typedef _Float16 half2_t __attribute__((ext_vector_type(2)));

__device__ __forceinline__ float fast_sig(float x) {
    return __fdividef(1.f, 1.f + __expf(-x));
}
__device__ __forceinline__ unsigned pack2h(float a, float b) {
    _Float16 ha = (_Float16)a, hb = (_Float16)b;
    unsigned short ua = __builtin_bit_cast(unsigned short, ha);
    unsigned short ub = __builtin_bit_cast(unsigned short, hb);
    return ((unsigned)ub << 16) | ua;
}
__device__ __forceinline__ float dot2(unsigned w, unsigned h, float acc) {
    return __builtin_amdgcn_fdot2(__builtin_bit_cast(half2_t, w),
                                  __builtin_bit_cast(half2_t, h), acc, false);
}

// ---------------- K0: pack weights ----------------
__global__ __launch_bounds__(256) void k0_pack(
    const float* __restrict__ Wh_w, const float* __restrict__ Wh_b,
    const float* __restrict__ Wi_w, const float* __restrict__ Wi_b,
    const float* __restrict__ Wf_w, const float* __restrict__ Wf_b,
    const float* __restrict__ Wd_w, const float* __restrict__ Wd_b,
    const float* __restrict__ Wg_w, const float* __restrict__ Wg_b,
    const float* __restrict__ Wo_w, const float* __restrict__ Wo_b,
    float* __restrict__ ws)
{
    const float* gw[5] = {Wi_w, Wf_w, Wd_w, Wg_w, Wo_w};
    const float* gb[5] = {Wi_b, Wf_b, Wd_b, Wg_b, Wo_b};
    int idx = blockIdx.x * 256 + threadIdx.x;
    if (idx < 196608) {            // W_all [r<64][col<3072]
        int r = idx / 3072, col = idx - r * 3072;
        float v;
        if (col < 512) {
            v = Wh_w[r * 512 + col] + Wh_w[(192 + r) * 512 + col]
              + Wh_w[(384 + r) * 512 + col] + Wh_w[(576 + r) * 512 + col];
        } else {
            int q = col - 512;
            int e = q / 640;
            int rem = q - e * 640;
            int g = rem >> 7, h = rem & 127;
            v = gw[g][(e * 192 + r) * 128 + h];
        }
        ws[OFF_WALL + idx] = v;
    } else if (idx < 327680) {     // WhhP: i = ((kq*64+ii)*2+cc)*256 + c2
        int i = idx - 196608;
        int c2 = i & 255;
        int cc = (i >> 8) & 1;
        int ii = (i >> 9) & 63;
        int kq = i >> 15;
        int col = 2 * c2 + cc;
        int d0 = kq * 128 + 2 * ii;
        int r0 = (d0 >> 7) * 192 + 64 + (d0 & 127);
        float w0 = Wh_w[r0 * 512 + col];
        float w1 = Wh_w[(r0 + 1) * 512 + col];
        reinterpret_cast<unsigned*>(ws + OFF_WHHH)[i] = pack2h(w0, w1);
    } else if (idx < 491520) {     // WgP: i = ((((e*4+kq)*5+g)*16+ii)*2+cc)*64 + p2
        int i = idx - 327680;
        int p2 = i & 63;
        int cc = (i >> 6) & 1;
        int ii = (i >> 7) & 15;
        int egk = i >> 11;
        int g = egk % 5;
        int ekq = egk / 5;
        int kq = ekq & 3;
        int e  = ekq >> 2;
        int h = 2 * p2 + cc;
        int j0 = kq * 32 + 2 * ii;
        float w0 = gw[g][(e * 192 + 64 + j0) * 128 + h];
        float w1 = gw[g][(e * 192 + 64 + j0 + 1) * 128 + h];
        reinterpret_cast<unsigned*>(ws + OFF_WGH)[i] = pack2h(w0, w1);
    }
    if (idx < 3072) {              // bias
        float v;
        if (idx < 512) v = Wh_b[idx];
        else {
            int q = idx - 512;
            int e = q / 640;
            int rem = q - e * 640;
            int g = rem >> 7, h = rem & 127;
            v = gb[g][e * 128 + h];
        }
        ws[OFF_BIAS + idx] = v;
    }
}

// ---------------- K1: XG[4096][3072] = X[4096][64] @ W_all + bias ----------------
__global__ __launch_bounds__(256) void k1_xproj(
    const float* __restrict__ x, const float* wsr, float* XG)
{
    __shared__ __align__(16) float XT[64 * 68];
    const float* W_all = wsr + OFF_WALL;
    const float* bias  = wsr + OFF_BIAS;
    int bid = blockIdx.x;
    int ct = bid % 48, rt = bid / 48;
    int r0 = rt * 64, c0 = ct * 64;
    for (int p = threadIdx.x; p < 4096; p += 256) {
        int i = p >> 6, k = p & 63;
        XT[k * 68 + i] = x[(r0 + i) * 64 + k];
    }
    __syncthreads();
    int col = c0 + (threadIdx.x & 63);
    int iq = threadIdx.x >> 6;
    float acc[16];
    #pragma unroll
    for (int r = 0; r < 16; r++) acc[r] = 0.f;
    const float* wp = W_all + col;
    #pragma unroll 4
    for (int k = 0; k < 64; k++) {
        float w = wp[k * 3072];
        const float4* xt4 = reinterpret_cast<const float4*>(&XT[k * 68 + iq * 16]);
        #pragma unroll
        for (int r4 = 0; r4 < 4; r4++) {
            float4 xv = xt4[r4];
            acc[r4 * 4 + 0] = fmaf(xv.x, w, acc[r4 * 4 + 0]);
            acc[r4 * 4 + 1] = fmaf(xv.y, w, acc[r4 * 4 + 1]);
            acc[r4 * 4 + 2] = fmaf(xv.z, w, acc[r4 * 4 + 2]);
            acc[r4 * 4 + 3] = fmaf(xv.w, w, acc[r4 * 4 + 3]);
        }
    }
    float bv = bias[col];
    #pragma unroll
    for (int r = 0; r < 16; r++) {
        int row = r0 + iq * 16 + r;
        XG[row * 3072 + col] = acc[r] + bv;
    }
}

// ---------------- K2: recurrence, one block = one batch element, all-LDS sync ----------------
// 128 blocks x 1024 threads. Full fp16 h-weight set register-resident per block
// (288 u32/thread). No cross-block communication at all.
__global__ __launch_bounds__(1024, 1) void k2_recur(
    const unsigned* __restrict__ WhhP,
    const unsigned* __restrict__ WgP,
    const float* __restrict__ XG,
    const float* __restrict__ dt_time,
    const float* __restrict__ alpha,
    float* __restrict__ Gst,
    float* __restrict__ lam_out)
{
    __shared__ __align__(16) unsigned hP[256];    // h_prev fp16 pairs (d=2p,2p+1)
    __shared__ __align__(16) float pA[4][512];    // phase-A partials [kq][col]
    __shared__ __align__(16) unsigned hsP[256];   // hs fp16 pairs
    __shared__ __align__(16) float pB[4][4][5][128]; // [kq][e][g][h]
    __shared__ float red[8];

    const int tid = threadIdx.x;
    const int b   = blockIdx.x;
    // phase A role: col-pair c2, K-quarter kq
    const int c2  = tid & 255;
    const int kq  = tid >> 8;
    // phase B role: h-pair p2, e-type eB, same kq
    const int p2  = tid & 63;
    const int eB  = (tid >> 6) & 3;
    // cell role (tid<512): e = tid>>7, l = tid&127
    const int eC  = tid >> 7;
    const int l   = tid & 127;

    // --- weights into registers (once) ---
    unsigned wa0[64], wa1[64];
    #pragma unroll
    for (int i = 0; i < 64; ++i) {
        wa0[i] = WhhP[((kq * 64 + i) * 2 + 0) * 256 + c2];
        wa1[i] = WhhP[((kq * 64 + i) * 2 + 1) * 256 + c2];
    }
    unsigned wg[5][2][16];
    #pragma unroll
    for (int g = 0; g < 5; ++g)
        #pragma unroll
        for (int cc = 0; cc < 2; ++cc)
            #pragma unroll
            for (int i = 0; i < 16; ++i)
                wg[g][cc][i] = WgP[((((eB * 4 + kq) * 5 + g) * 16 + i) * 2 + cc) * 64 + p2];

    const float av = (tid < 512) ? alpha[tid] : 0.f;
    float cst = 0.f;

    #pragma unroll 1
    for (int t = 0; t < 32; ++t) {
        const int row = t * 128 + b;
        // prefetch XG slice (used after barriers; overlaps with phase A)
        float xg0 = 0.f, x0 = 0.f, x1 = 0.f, x2 = 0.f, x3 = 0.f, x4 = 0.f;
        if (tid < 512) {
            const float* bp = XG + (size_t)row * 3072;
            xg0 = bp[tid];
            const float* gp = bp + 512 + eC * 640 + l;
            x0 = gp[0]; x1 = gp[128]; x2 = gp[256]; x3 = gp[384]; x4 = gp[512];
        }
        // phase A: hs partials over K-quarter (uniform-address broadcast reads)
        if (t > 0) {
            float a0 = 0.f, a1 = 0.f;
            const uint4* h4 = reinterpret_cast<const uint4*>(hP) + kq * 16;
            #pragma unroll
            for (int i4 = 0; i4 < 16; ++i4) {
                uint4 hp = h4[i4];
                a0 = dot2(wa0[i4 * 4 + 0], hp.x, a0); a1 = dot2(wa1[i4 * 4 + 0], hp.x, a1);
                a0 = dot2(wa0[i4 * 4 + 1], hp.y, a0); a1 = dot2(wa1[i4 * 4 + 1], hp.y, a1);
                a0 = dot2(wa0[i4 * 4 + 2], hp.z, a0); a1 = dot2(wa1[i4 * 4 + 2], hp.z, a1);
                a0 = dot2(wa0[i4 * 4 + 3], hp.w, a0); a1 = dot2(wa1[i4 * 4 + 3], hp.w, a1);
            }
            float2 w; w.x = a0; w.y = a1;
            *reinterpret_cast<float2*>(&pA[kq][2 * c2]) = w;
        }
        __syncthreads();   // bar1: pA ready
        if (tid < 512) {
            float hsv = xg0;
            if (t > 0) hsv += pA[0][tid] + pA[1][tid] + pA[2][tid] + pA[3][tid];
            float hi = __shfl_down(hsv, 1, 64);
            if ((tid & 1) == 0) hsP[tid >> 1] = pack2h(hsv, hi);
        }
        __syncthreads();   // bar2: hsP ready
        // phase B: 5 gate partials x 2 h-cols over K-quarter
        {
            float accB[5][2];
            #pragma unroll
            for (int g = 0; g < 5; ++g) { accB[g][0] = 0.f; accB[g][1] = 0.f; }
            const uint4* hs4 = reinterpret_cast<const uint4*>(hsP) + (eB * 16 + kq * 4);
            #pragma unroll
            for (int i4 = 0; i4 < 4; ++i4) {
                uint4 hp = hs4[i4];
                #pragma unroll
                for (int g = 0; g < 5; ++g) {
                    accB[g][0] = dot2(wg[g][0][i4 * 4 + 0], hp.x, accB[g][0]);
                    accB[g][1] = dot2(wg[g][1][i4 * 4 + 0], hp.x, accB[g][1]);
                    accB[g][0] = dot2(wg[g][0][i4 * 4 + 1], hp.y, accB[g][0]);
                    accB[g][1] = dot2(wg[g][1][i4 * 4 + 1], hp.y, accB[g][1]);
                    accB[g][0] = dot2(wg[g][0][i4 * 4 + 2], hp.z, accB[g][0]);
                    accB[g][1] = dot2(wg[g][1][i4 * 4 + 2], hp.z, accB[g][1]);
                    accB[g][0] = dot2(wg[g][0][i4 * 4 + 3], hp.w, accB[g][0]);
                    accB[g][1] = dot2(wg[g][1][i4 * 4 + 3], hp.w, accB[g][1]);
                }
            }
            #pragma unroll
            for (int g = 0; g < 5; ++g) {
                float2 w; w.x = accB[g][0]; w.y = accB[g][1];
                *reinterpret_cast<float2*>(&pB[kq][eB][g][2 * p2]) = w;
            }
        }
        __syncthreads();   // bar3: pB ready
        if (tid < 512) {
            float ai = pB[0][eC][0][l] + pB[1][eC][0][l] + pB[2][eC][0][l] + pB[3][eC][0][l] + x0;
            float af = pB[0][eC][1][l] + pB[1][eC][1][l] + pB[2][eC][1][l] + pB[3][eC][1][l] + x1;
            float ad = pB[0][eC][2][l] + pB[1][eC][2][l] + pB[2][eC][2][l] + pB[3][eC][2][l] + x2;
            float ag = pB[0][eC][3][l] + pB[1][eC][3][l] + pB[2][eC][3][l] + pB[3][eC][3][l] + x3;
            float ao = pB[0][eC][4][l] + pB[1][eC][4][l] + pB[2][eC][4][l] + pB[3][eC][4][l] + x4;
            float ig = fast_sig(ai);
            float fg = fast_sig(af);
            float dl = __expf(ad);
            float gt = tanhf(ag);
            float og = fast_sig(ao);
            float gc = fmaf(fg, cst, ig * gt);
            float df = cst - gc;
            float dtv = dt_time[row];
            cst = fmaf(df, __expf(-dl * dtv), gc);
            float hn = og * tanhf(cst);
            size_t go = (size_t)row * 512 + tid;
            Gst[0 * GST_PLANE + go] = gc;
            Gst[1 * GST_PLANE + go] = df;
            Gst[2 * GST_PLANE + go] = dl;
            Gst[3 * GST_PLANE + go] = og;
            // pack h_new -> hP for next step (pairs within same wave)
            float hi = __shfl_down(hn, 1, 64);
            if ((tid & 1) == 0) hP[tid >> 1] = pack2h(hn, hi);
            // lambda partials
            float lm = av * hn;
            #pragma unroll
            for (int off = 32; off > 0; off >>= 1) lm += __shfl_down(lm, off, 64);
            if ((tid & 63) == 0) red[tid >> 6] = lm;
        }
        __syncthreads();   // bar4: hP + red ready
        if (tid < 4) lam_out[row * 4 + tid] = red[2 * tid] + red[2 * tid + 1];
    }
}

// ---------------- K3: trapezoid integrals, 1 block per (t,b) ----------------
__global__ __launch_bounds__(256) void k3_trap(
    const float* __restrict__ Gst, const float* __restrict__ dt_time,
    const float* __restrict__ alpha, float* __restrict__ integ_out)
{
    __shared__ float red[4][2];
    const int row = blockIdx.x;
    const int tid = threadIdx.x;
    const float dtv = dt_time[row];
    const int base = row * 512;
    const int pA = tid, pB = tid + 256;
    float gcA = Gst[0 * GST_PLANE + base + pA];
    float gcB = Gst[0 * GST_PLANE + base + pB];
    float dfA = Gst[1 * GST_PLANE + base + pA];
    float dfB = Gst[1 * GST_PLANE + base + pB];
    float dlA = Gst[2 * GST_PLANE + base + pA];
    float dlB = Gst[2 * GST_PLANE + base + pB];
    float oA  = Gst[3 * GST_PLANE + base + pA];
    float oB  = Gst[3 * GST_PLANE + base + pB];
    float aoA = alpha[pA] * oA;
    float aoB = alpha[pB] * oB;
    float g2A = 2.f * gcA, d2A = 2.f * dfA;
    float g2B = 2.f * gcB, d2B = 2.f * dfB;
    float qA = dlA * dtv, qB = dlB * dtv;
    float rA = __expf(-qA * 0.01f);
    float rB = __expf(-qB * 0.01f);
    float E100A = __expf(-qA);
    float E100B = __expf(-qB);
    float sA = 0.5f * (__fdividef(1.f, __expf(g2A + d2A) + 1.f)
                     + __fdividef(1.f, __expf(fmaf(d2A, E100A, g2A)) + 1.f));
    float sB = 0.5f * (__fdividef(1.f, __expf(g2B + d2B) + 1.f)
                     + __fdividef(1.f, __expf(fmaf(d2B, E100B, g2B)) + 1.f));
    float EA = rA, EB = rB;
    for (int k = 1; k < 100; k++) {
        sA += __fdividef(1.f, __expf(fmaf(d2A, EA, g2A)) + 1.f);
        sB += __fdividef(1.f, __expf(fmaf(d2B, EB, g2B)) + 1.f);
        EA *= rA;
        EB *= rB;
    }
    float vA = aoA * (100.f - 2.f * sA);
    float vB = aoB * (100.f - 2.f * sB);
    #pragma unroll
    for (int off = 32; off > 0; off >>= 1) {
        vA += __shfl_down(vA, off, 64);
        vB += __shfl_down(vB, off, 64);
    }
    const int wv = tid >> 6;
    if ((tid & 63) == 0) { red[wv][0] = vA; red[wv][1] = vB; }
    __syncthreads();
    if (tid < 4) {
        float v = (tid < 2) ? (red[2 * tid][0] + red[2 * tid + 1][0])
                            : (red[2 * (tid - 2)][1] + red[2 * (tid - 2) + 1][1]);
        integ_out[row * 4 + tid] = v * (dtv * 0.01f);
    }
}

extern "C" void kernel_launch(void* const* d_in, const int* in_sizes, int n_in,
                              void* d_out, int out_size, void* d_ws, size_t ws_size,
                              hipStream_t stream)
{
    const float* x_time  = (const float*)d_in[0];
    const float* dt_time = (const float*)d_in[1];
    const float* Wh_w = (const float*)d_in[2];
    const float* Wh_b = (const float*)d_in[3];
    const float* Wi_w = (const float*)d_in[4];
    const float* Wi_b = (const float*)d_in[5];
    const float* Wf_w = (const float*)d_in[6];
    const float* Wf_b = (const float*)d_in[7];
    const float* Wd_w = (const float*)d_in[8];
    const float* Wd_b = (const float*)d_in[9];
    const float* Wg_w = (const float*)d_in[10];
    const float* Wg_b = (const float*)d_in[11];
    const float* Wo_w = (const float*)d_in[12];
    const float* Wo_b = (const float*)d_in[13];
    const float* alpha = (const float*)d_in[14];

    float* ws = (float*)d_ws;
    float* XG   = ws + OFF_XG;
    float* Gst  = ws + OFF_GST;
    float* lam_out   = (float*)d_out;
    float* integ_out = lam_out + 32 * 128 * 4;

    k0_pack<<<3072, 256, 0, stream>>>(Wh_w, Wh_b, Wi_w, Wi_b, Wf_w, Wf_b,
                                      Wd_w, Wd_b, Wg_w, Wg_b, Wo_w, Wo_b, ws);
    k1_xproj<<<3072, 256, 0, stream>>>(x_time, ws, XG);
    k2_recur<<<128, 1024, 0, stream>>>(
        (const unsigned*)(ws + OFF_WHHH), (const unsigned*)(ws + OFF_WGH),
        XG, dt_time, alpha, Gst, lam_out);
    k3_trap<<<4096, 256, 0, stream>>>(Gst, dt_time, alpha, integ_out);
}

// Round 7
// 269.719 us; speedup vs baseline: 7.5692x; 7.5692x over previous
//
#include <hip/hip_runtime.h>

// stackCLSTM: T=32, B=128, I=64, H=128, E=4, N_TRAP=100
// ws layout (float-word offsets):
//   W_all  [64][3072] fp32        @ 0         (196608)
//   bias   [3072] fp32            @ 196608    (3072)
//   WhhH   [e][kq][64][128] u32   @ 199680    (131072)  fp16-pair packed Whh h-part
//   WgH    [e][kq][16][5][128] u32@ 330752    (163840)  fp16-pair packed gate h-part
//   XG     [4096][3072] fp32      @ 494592    (12582912)
//   Gst    [4][4096*512] fp32     @ 13077504  (8388608)
//   hbuf   [2][64][4][2][64] u32  @ 21466112  (65536)   fp16-pair packed h state
//   flags  [64][32] int           @ 21531648  (2048)
#define OFF_WALL   0
#define OFF_BIAS   196608
#define OFF_WHHH   199680
#define OFF_WGH    330752
#define OFF_XG     494592
#define OFF_GST    13077504
#define OFF_HBUF   21466112
#define OFF_FLAGS  21531648
#define GST_PLANE  2097152

typedef _Float16 half2_t __attribute__((ext_vector_type(2)));

__device__ __forceinline__ float fast_sig(float x) {
    return __fdividef(1.f, 1.f + __expf(-x));
}
__device__ __forceinline__ unsigned pack2h(float a, float b) {
    _Float16 ha = (_Float16)a, hb = (_Float16)b;
    unsigned short ua = __builtin_bit_cast(unsigned short, ha);
    unsigned short ub = __builtin_bit_cast(unsigned short, hb);
    return ((unsigned)ub << 16) | ua;
}
__device__ __forceinline__ float dot2(unsigned w, unsigned h, float acc) {
    return __builtin_amdgcn_fdot2(__builtin_bit_cast(half2_t, w),
                                  __builtin_bit_cast(half2_t, h), acc, false);
}

// ---------------- K0: pack weights (fp32 W_all + fp16 h-part) + zero flags ----------------
__global__ __launch_bounds__(256) void k0_pack(
    const float* __restrict__ Wh_w, const float* __restrict__ Wh_b,
    const float* __restrict__ Wi_w, const float* __restrict__ Wi_b,
    const float* __restrict__ Wf_w, const float* __restrict__ Wf_b,
    const float* __restrict__ Wd_w, const float* __restrict__ Wd_b,
    const float* __restrict__ Wg_w, const float* __restrict__ Wg_b,
    const float* __restrict__ Wo_w, const float* __restrict__ Wo_b,
    float* __restrict__ ws)
{
    const float* gw[5] = {Wi_w, Wf_w, Wd_w, Wg_w, Wo_w};
    const float* gb[5] = {Wi_b, Wf_b, Wd_b, Wg_b, Wo_b};
    int idx = blockIdx.x * 256 + threadIdx.x;
    if (idx < 196608) {            // W_all [r<64][col<3072]
        int r = idx / 3072, col = idx - r * 3072;
        float v;
        if (col < 512) {
            v = Wh_w[r * 512 + col] + Wh_w[(192 + r) * 512 + col]
              + Wh_w[(384 + r) * 512 + col] + Wh_w[(576 + r) * 512 + col];
        } else {
            int q = col - 512;
            int e = q / 640;
            int rem = q - e * 640;
            int g = rem >> 7, h = rem & 127;
            v = gw[g][(e * 192 + r) * 128 + h];
        }
        ws[OFF_WALL + idx] = v;
    } else if (idx < 327680) {     // WhhH [e][kq][64 ii][128 lane] packed pairs
        int i = idx - 196608;
        int lane = i & 127;
        int ii = (i >> 7) & 63;
        int kq = (i >> 13) & 3;
        int e  = i >> 15;
        int k0 = kq * 128 + 2 * ii, k1 = k0 + 1;
        int r0 = (k0 >> 7) * 192 + 64 + (k0 & 127);
        int r1 = (k1 >> 7) * 192 + 64 + (k1 & 127);
        float w0 = Wh_w[r0 * 512 + e * 128 + lane];
        float w1 = Wh_w[r1 * 512 + e * 128 + lane];
        reinterpret_cast<unsigned*>(ws + OFF_WHHH)[i] = pack2h(w0, w1);
    } else if (idx < 491520) {     // WgH [e][kq][16 ii][5 g][128 lane]
        int i = idx - 327680;
        int lane = i & 127;
        int gg = (i >> 7) % 5;
        int rest = (i >> 7) / 5;
        int ii = rest & 15;
        int kq = (rest >> 4) & 3;
        int e  = rest >> 6;
        int k0 = kq * 32 + 2 * ii, k1 = k0 + 1;
        float w0 = gw[gg][(e * 192 + 64 + k0) * 128 + lane];
        float w1 = gw[gg][(e * 192 + 64 + k1) * 128 + lane];
        reinterpret_cast<unsigned*>(ws + OFF_WGH)[i] = pack2h(w0, w1);
    }
    if (idx < 3072) {              // bias
        float v;
        if (idx < 512) v = Wh_b[idx];
        else {
            int q = idx - 512;
            int e = q / 640;
            int rem = q - e * 640;
            int g = rem >> 7, h = rem & 127;
            v = gb[g][e * 128 + h];
        }
        ws[OFF_BIAS + idx] = v;
    }
    if (idx < 2048) {              // zero sync flags every launch (graph-safe)
        reinterpret_cast<int*>(ws + OFF_FLAGS)[idx] = 0;
    }
}

// ---------------- K1: XG[4096][3072] = X[4096][64] @ W_all + bias ----------------
__global__ __launch_bounds__(256) void k1_xproj(
    const float* __restrict__ x, const float* wsr, float* XG)
{
    __shared__ __align__(16) float XT[64 * 68];
    const float* W_all = wsr + OFF_WALL;
    const float* bias  = wsr + OFF_BIAS;
    int bid = blockIdx.x;
    int ct = bid % 48, rt = bid / 48;
    int r0 = rt * 64, c0 = ct * 64;
    for (int p = threadIdx.x; p < 4096; p += 256) {
        int i = p >> 6, k = p & 63;
        XT[k * 68 + i] = x[(r0 + i) * 64 + k];
    }
    __syncthreads();
    int col = c0 + (threadIdx.x & 63);
    int iq = threadIdx.x >> 6;
    float acc[16];
    #pragma unroll
    for (int r = 0; r < 16; r++) acc[r] = 0.f;
    const float* wp = W_all + col;
    #pragma unroll 4
    for (int k = 0; k < 64; k++) {
        float w = wp[k * 3072];
        const float4* xt4 = reinterpret_cast<const float4*>(&XT[k * 68 + iq * 16]);
        #pragma unroll
        for (int r4 = 0; r4 < 4; r4++) {
            float4 xv = xt4[r4];
            acc[r4 * 4 + 0] = fmaf(xv.x, w, acc[r4 * 4 + 0]);
            acc[r4 * 4 + 1] = fmaf(xv.y, w, acc[r4 * 4 + 1]);
            acc[r4 * 4 + 2] = fmaf(xv.z, w, acc[r4 * 4 + 2]);
            acc[r4 * 4 + 3] = fmaf(xv.w, w, acc[r4 * 4 + 3]);
        }
    }
    float bv = bias[col];
    #pragma unroll
    for (int r = 0; r < 16; r++) {
        int row = r0 + iq * 16 + r;
        XG[row * 3072 + col] = acc[r] + bv;
    }
}

// ---------------- K2: recurrence, register-resident fp16 weights ----------------
// 256 blocks x 512 threads, 1 block/CU (launch_bounds(512,1) -> VGPR cap 256 so
// the 144 weight words/thread actually STAY in registers; (512,2)'s 128 cap forced
// per-step L2 re-streaming = R4's 2.1us/step L2-roofline phase).
// Group of 4 blocks (one per e) = 1 batch pair. K-dim split 4-way (kq=tid>>7).
// Sync: relaxed agent-scope atomics only (IC-direct), no acquire/release cache
// maintenance; __syncthreads' vmcnt(0) drain orders h-stores before the flag add.
__global__ __launch_bounds__(512, 1) void k2_recur(
    const unsigned* __restrict__ WhhH,
    const unsigned* __restrict__ WgH,
    const float* __restrict__ XG,
    const float* __restrict__ dt_time,
    const float* __restrict__ alpha,
    float* __restrict__ Gst,
    unsigned* __restrict__ hbuf,
    int* __restrict__ flags,
    float* __restrict__ lam_out)
{
    __shared__ __align__(16) unsigned hL[256][2];   // [pair p=e*64+j/2][slot]
    __shared__ __align__(16) float hsF[2][128];
    __shared__ float pA[4][2][128];
    __shared__ float pB[4][2][5][128];
    __shared__ float red[4];
    const int tid = threadIdx.x;
    const int bid = blockIdx.x;
    const int e   = (bid >> 3) & 3;
    const int grp = (bid & 7) | ((bid >> 5) << 3);
    const int b0  = grp * 2;
    const int kq  = tid >> 7;          // K-quarter
    const int lane = tid & 127;        // output index (col / h')
    const int s = (tid >> 7) & 1, l = lane;   // roles for tid<256

    // --- load weights into registers (once) ---
    unsigned wa[64];
    #pragma unroll
    for (int i = 0; i < 64; i++)
        wa[i] = WhhH[((e * 4 + kq) * 64 + i) * 128 + lane];
    unsigned wg[5][16];
    #pragma unroll
    for (int i = 0; i < 16; i++) {
        #pragma unroll
        for (int g = 0; g < 5; g++)
            wg[g][i] = WgH[(((e * 4 + kq) * 16 + i) * 5 + g) * 128 + lane];
    }
    const float av = alpha[e * 128 + lane];
    int* gflag = flags + grp * 32;
    float cst = 0.f;

    for (int t = 0; t < 32; ++t) {
        const int row0 = t * 128 + b0;
        // (1) prefetch this step's XG slice (issued before the wait)
        float xg0 = 0.f, xgg0 = 0.f, xgg1 = 0.f, xgg2 = 0.f, xgg3 = 0.f, xgg4 = 0.f;
        if (tid < 256) {
            const float* base = XG + (size_t)(row0 + s) * 3072;
            xg0 = base[e * 128 + l];
            const float* gp = base + 512 + e * 640 + l;
            xgg0 = gp[0]; xgg1 = gp[128]; xgg2 = gp[256]; xgg3 = gp[384]; xgg4 = gp[512];
        }
        if (t > 0) {
            // (2) wait for group step t-1 (relaxed poll, no cache maintenance)
            if (tid == 0) {
                while (__hip_atomic_load(&gflag[t - 1], __ATOMIC_RELAXED,
                                         __HIP_MEMORY_SCOPE_AGENT) < 4)
                    __builtin_amdgcn_s_sleep(1);
            }
            __syncthreads();
            asm volatile("" ::: "memory");
            // (3) stage h (parity t&1) -> LDS via IC-direct relaxed atomic loads
            {
                const unsigned* src = hbuf + (size_t)((t & 1) * 64 + grp) * 512;
                unsigned v = __hip_atomic_load(&src[tid], __ATOMIC_RELAXED,
                                               __HIP_MEMORY_SCOPE_AGENT);
                int eh = tid >> 7, sh = (tid >> 6) & 1, p = tid & 63;
                hL[eh * 64 + p][sh] = v;
            }
            __syncthreads();
            // (4) phase A: partial hs dots over K-quarter
            float a0 = 0.f, a1 = 0.f;
            #pragma unroll
            for (int i = 0; i < 64; i++) {
                uint2 hp = *reinterpret_cast<const uint2*>(&hL[kq * 64 + i][0]);
                a0 = dot2(wa[i], hp.x, a0);
                a1 = dot2(wa[i], hp.y, a1);
            }
            pA[kq][0][lane] = a0;
            pA[kq][1][lane] = a1;
            __syncthreads();
            if (tid < 256) {
                float hs = pA[0][s][l] + pA[1][s][l] + pA[2][s][l] + pA[3][s][l] + xg0;
                hsF[s][l] = hs;
            }
        } else {
            if (tid < 256) hsF[s][l] = xg0;   // h=0 at t=0
        }
        __syncthreads();
        // (5) phase B: 5 gate partial dots over K-quarter (K=128)
        float b0a = 0.f, b1a = 0.f, b2a = 0.f, b3a = 0.f, b4a = 0.f;
        float b0b = 0.f, b1b = 0.f, b2b = 0.f, b3b = 0.f, b4b = 0.f;
        #pragma unroll
        for (int i = 0; i < 16; i++) {
            float2 f0 = *reinterpret_cast<const float2*>(&hsF[0][kq * 32 + 2 * i]);
            float2 f1 = *reinterpret_cast<const float2*>(&hsF[1][kq * 32 + 2 * i]);
            unsigned h0 = pack2h(f0.x, f0.y);
            unsigned h1 = pack2h(f1.x, f1.y);
            b0a = dot2(wg[0][i], h0, b0a); b0b = dot2(wg[0][i], h1, b0b);
            b1a = dot2(wg[1][i], h0, b1a); b1b = dot2(wg[1][i], h1, b1b);
            b2a = dot2(wg[2][i], h0, b2a); b2b = dot2(wg[2][i], h1, b2b);
            b3a = dot2(wg[3][i], h0, b3a); b3b = dot2(wg[3][i], h1, b3b);
            b4a = dot2(wg[4][i], h0, b4a); b4b = dot2(wg[4][i], h1, b4b);
        }
        pB[kq][0][0][lane] = b0a; pB[kq][0][1][lane] = b1a; pB[kq][0][2][lane] = b2a;
        pB[kq][0][3][lane] = b3a; pB[kq][0][4][lane] = b4a;
        pB[kq][1][0][lane] = b0b; pB[kq][1][1][lane] = b1b; pB[kq][1][2][lane] = b2b;
        pB[kq][1][3][lane] = b3b; pB[kq][1][4][lane] = b4b;
        __syncthreads();
        // (6) cell update + outputs (tid<256: s,l)
        if (tid < 256) {
            float ai = pB[0][s][0][l] + pB[1][s][0][l] + pB[2][s][0][l] + pB[3][s][0][l] + xgg0;
            float af = pB[0][s][1][l] + pB[1][s][1][l] + pB[2][s][1][l] + pB[3][s][1][l] + xgg1;
            float ad = pB[0][s][2][l] + pB[1][s][2][l] + pB[2][s][2][l] + pB[3][s][2][l] + xgg2;
            float ag = pB[0][s][3][l] + pB[1][s][3][l] + pB[2][s][3][l] + pB[3][s][3][l] + xgg3;
            float ao = pB[0][s][4][l] + pB[1][s][4][l] + pB[2][s][4][l] + pB[3][s][4][l] + xgg4;
            float ig = fast_sig(ai);
            float fg = fast_sig(af);
            float dl = __expf(ad);
            float gt = tanhf(ag);
            float og = fast_sig(ao);
            float gc = fmaf(fg, cst, ig * gt);
            float df = cst - gc;
            float dtv = dt_time[row0 + s];
            cst = fmaf(df, __expf(-dl * dtv), gc);
            float hn = og * tanhf(cst);
            size_t go = (size_t)(row0 + s) * 512 + e * 128 + l;
            Gst[0 * GST_PLANE + go] = gc;
            Gst[1 * GST_PLANE + go] = df;
            Gst[2 * GST_PLANE + go] = dl;
            Gst[3 * GST_PLANE + go] = og;
            // pack h_new pairs -> hbuf parity (t+1)&1 via IC-direct atomic store
            float hi = __shfl_down(hn, 1, 64);
            if ((l & 1) == 0) {
                unsigned* dst = hbuf
                    + (size_t)(((t + 1) & 1) * 64 + grp) * 512
                    + (e * 2 + s) * 64 + (l >> 1);
                __hip_atomic_store(dst, pack2h(hn, hi), __ATOMIC_RELAXED,
                                   __HIP_MEMORY_SCOPE_AGENT);
            }
            // lambda reduce
            float lm = av * hn;
            #pragma unroll
            for (int off = 32; off > 0; off >>= 1) lm += __shfl_down(lm, off, 64);
            if ((tid & 63) == 0) red[tid >> 6] = lm;
        }
        __syncthreads();   // drains vmcnt(0): h stores are at IC before flag add
        if (tid == 0) {
            lam_out[(row0 + 0) * 4 + e] = red[0] + red[1];
            lam_out[(row0 + 1) * 4 + e] = red[2] + red[3];
            __hip_atomic_fetch_add(&gflag[t], 1, __ATOMIC_RELAXED,
                                   __HIP_MEMORY_SCOPE_AGENT);
        }
    }
}

// ---------------- K3: trapezoid integrals, 1 block per (t,b) ----------------
__global__ __launch_bounds__(256) void k3_trap(
    const float* __restrict__ Gst, const float* __restrict__ dt_time,
    const float* __restrict__ alpha, float* __restrict__ integ_out)
{
    __shared__ float red[4][2];
    const int row = blockIdx.x;
    const int tid = threadIdx.x;
    const float dtv = dt_time[row];
    const int base = row * 512;
    const int pA = tid, pB = tid + 256;
    float gcA = Gst[0 * GST_PLANE + base + pA];
    float gcB = Gst[0 * GST_PLANE + base + pB];
    float dfA = Gst[1 * GST_PLANE + base + pA];
    float dfB = Gst[1 * GST_PLANE + base + pB];
    float dlA = Gst[2 * GST_PLANE + base + pA];
    float dlB = Gst[2 * GST_PLANE + base + pB];
    float oA  = Gst[3 * GST_PLANE + base + pA];
    float oB  = Gst[3 * GST_PLANE + base + pB];
    float aoA = alpha[pA] * oA;
    float aoB = alpha[pB] * oB;
    float g2A = 2.f * gcA, d2A = 2.f * dfA;
    float g2B = 2.f * gcB, d2B = 2.f * dfB;
    float qA = dlA * dtv, qB = dlB * dtv;
    float rA = __expf(-qA * 0.01f);
    float rB = __expf(-qB * 0.01f);
    float E100A = __expf(-qA);
    float E100B = __expf(-qB);
    float sA = 0.5f * (__fdividef(1.f, __expf(g2A + d2A) + 1.f)
                     + __fdividef(1.f, __expf(fmaf(d2A, E100A, g2A)) + 1.f));
    float sB = 0.5f * (__fdividef(1.f, __expf(g2B + d2B) + 1.f)
                     + __fdividef(1.f, __expf(fmaf(d2B, E100B, g2B)) + 1.f));
    float EA = rA, EB = rB;
    for (int k = 1; k < 100; k++) {
        sA += __fdividef(1.f, __expf(fmaf(d2A, EA, g2A)) + 1.f);
        sB += __fdividef(1.f, __expf(fmaf(d2B, EB, g2B)) + 1.f);
        EA *= rA;
        EB *= rB;
    }
    float vA = aoA * (100.f - 2.f * sA);
    float vB = aoB * (100.f - 2.f * sB);
    #pragma unroll
    for (int off = 32; off > 0; off >>= 1) {
        vA += __shfl_down(vA, off, 64);
        vB += __shfl_down(vB, off, 64);
    }
    const int wv = tid >> 6;
    if ((tid & 63) == 0) { red[wv][0] = vA; red[wv][1] = vB; }
    __syncthreads();
    if (tid < 4) {
        float v = (tid < 2) ? (red[2 * tid][0] + red[2 * tid + 1][0])
                            : (red[2 * (tid - 2)][1] + red[2 * (tid - 2) + 1][1]);
        integ_out[row * 4 + tid] = v * (dtv * 0.01f);
    }
}

extern "C" void kernel_launch(void* const* d_in, const int* in_sizes, int n_in,
                              void* d_out, int out_size, void* d_ws, size_t ws_size,
                              hipStream_t stream)
{
    const float* x_time  = (const float*)d_in[0];
    const float* dt_time = (const float*)d_in[1];
    const float* Wh_w = (const float*)d_in[2];
    const float* Wh_b = (const float*)d_in[3];
    const float* Wi_w = (const float*)d_in[4];
    const float* Wi_b = (const float*)d_in[5];
    const float* Wf_w = (const float*)d_in[6];
    const float* Wf_b = (const float*)d_in[7];
    const float* Wd_w = (const float*)d_in[8];
    const float* Wd_b = (const float*)d_in[9];
    const float* Wg_w = (const float*)d_in[10];
    const float* Wg_b = (const float*)d_in[11];
    const float* Wo_w = (const float*)d_in[12];
    const float* Wo_b = (const float*)d_in[13];
    const float* alpha = (const float*)d_in[14];

    float* ws = (float*)d_ws;
    float* XG   = ws + OFF_XG;
    float* Gst  = ws + OFF_GST;
    unsigned* hbuf = (unsigned*)(ws + OFF_HBUF);
    int*   flags = (int*)(ws + OFF_FLAGS);
    float* lam_out   = (float*)d_out;
    float* integ_out = lam_out + 32 * 128 * 4;

    k0_pack<<<3072, 256, 0, stream>>>(Wh_w, Wh_b, Wi_w, Wi_b, Wf_w, Wf_b,
                                      Wd_w, Wd_b, Wg_w, Wg_b, Wo_w, Wo_b, ws);
    k1_xproj<<<3072, 256, 0, stream>>>(x_time, ws, XG);
    k2_recur<<<256, 512, 0, stream>>>(
        (const unsigned*)(ws + OFF_WHHH), (const unsigned*)(ws + OFF_WGH),
        XG, dt_time, alpha, Gst, hbuf, flags, lam_out);
    k3_trap<<<4096, 256, 0, stream>>>(Gst, dt_time, alpha, integ_out);
}

// Round 9
// 263.891 us; speedup vs baseline: 7.7364x; 1.0221x over previous
//
#include <hip/hip_runtime.h>

// stackCLSTM: T=32, B=128, I=64, H=128, E=4, N_TRAP=100
// ws layout (float-word offsets):
//   W_all  [64][3072] fp32        @ 0         (196608)
//   bias   [3072] fp32            @ 196608    (3072)
//   WhhH   [e][kq][i4][lane][q]   @ 199680    (131072)  fp16-pair packed Whh h-part (uint4 rows)
//   WgH    [e][kq][16][5][128] u32@ 330752    (163840)  fp16-pair packed gate h-part
//   XG     [4096][3072] fp32      @ 494592    (12582912)
//   Gst    [4][4096*512] fp32     @ 13077504  (8388608)
//   hbuf   [2][64][4][2][64] u32  @ 21466112  (65536)   fp16-pair packed h state
//   flags  [64][32] int           @ 21531648  (2048)
#define OFF_WALL   0
#define OFF_BIAS   196608
#define OFF_WHHH   199680
#define OFF_WGH    330752
#define OFF_XG     494592
#define OFF_GST    13077504
#define OFF_HBUF   21466112
#define OFF_FLAGS  21531648
#define GST_PLANE  2097152

typedef _Float16 half2_t __attribute__((ext_vector_type(2)));

__device__ __forceinline__ float fast_sig(float x) {
    return __fdividef(1.f, 1.f + __expf(-x));
}
__device__ __forceinline__ unsigned pack2h(float a, float b) {
    _Float16 ha = (_Float16)a, hb = (_Float16)b;
    unsigned short ua = __builtin_bit_cast(unsigned short, ha);
    unsigned short ub = __builtin_bit_cast(unsigned short, hb);
    return ((unsigned)ub << 16) | ua;
}
__device__ __forceinline__ float dot2(unsigned w, unsigned h, float acc) {
    return __builtin_amdgcn_fdot2(__builtin_bit_cast(half2_t, w),
                                  __builtin_bit_cast(half2_t, h), acc, false);
}

// ---------------- K0: pack weights (fp32 W_all + fp16 h-part) + zero flags ----------------
__global__ __launch_bounds__(256) void k0_pack(
    const float* __restrict__ Wh_w, const float* __restrict__ Wh_b,
    const float* __restrict__ Wi_w, const float* __restrict__ Wi_b,
    const float* __restrict__ Wf_w, const float* __restrict__ Wf_b,
    const float* __restrict__ Wd_w, const float* __restrict__ Wd_b,
    const float* __restrict__ Wg_w, const float* __restrict__ Wg_b,
    const float* __restrict__ Wo_w, const float* __restrict__ Wo_b,
    float* __restrict__ ws)
{
    const float* gw[5] = {Wi_w, Wf_w, Wd_w, Wg_w, Wo_w};
    const float* gb[5] = {Wi_b, Wf_b, Wd_b, Wg_b, Wo_b};
    int idx = blockIdx.x * 256 + threadIdx.x;
    if (idx < 196608) {            // W_all [r<64][col<3072]
        int r = idx / 3072, col = idx - r * 3072;
        float v;
        if (col < 512) {
            v = Wh_w[r * 512 + col] + Wh_w[(192 + r) * 512 + col]
              + Wh_w[(384 + r) * 512 + col] + Wh_w[(576 + r) * 512 + col];
        } else {
            int q = col - 512;
            int e = q / 640;
            int rem = q - e * 640;
            int g = rem >> 7, h = rem & 127;
            v = gw[g][(e * 192 + r) * 128 + h];
        }
        ws[OFF_WALL + idx] = v;
    } else if (idx < 327680) {     // WhhH [e][kq][i4][lane][q]  (uint4-per-lane rows)
        int i = idx - 196608;
        int q    = i & 3;
        int lane = (i >> 2) & 127;
        int i4   = (i >> 9) & 15;
        int kq   = (i >> 13) & 3;
        int e    = i >> 15;
        int kp = i4 * 4 + q;                 // k-pair index within kq slice
        int k0 = kq * 128 + 2 * kp;
        int r0 = (k0 >> 7) * 192 + 64 + (k0 & 127);
        float w0 = Wh_w[r0 * 512 + e * 128 + lane];
        float w1 = Wh_w[(r0 + 1) * 512 + e * 128 + lane];
        reinterpret_cast<unsigned*>(ws + OFF_WHHH)[i] = pack2h(w0, w1);
    } else if (idx < 491520) {     // WgH [e][kq][16 ii][5 g][128 lane]
        int i = idx - 327680;
        int lane = i & 127;
        int gg = (i >> 7) % 5;
        int rest = (i >> 7) / 5;
        int ii = rest & 15;
        int kq = (rest >> 4) & 3;
        int e  = rest >> 6;
        int k0 = kq * 32 + 2 * ii, k1 = k0 + 1;
        float w0 = gw[gg][(e * 192 + 64 + k0) * 128 + lane];
        float w1 = gw[gg][(e * 192 + 64 + k1) * 128 + lane];
        reinterpret_cast<unsigned*>(ws + OFF_WGH)[i] = pack2h(w0, w1);
    }
    if (idx < 3072) {              // bias
        float v;
        if (idx < 512) v = Wh_b[idx];
        else {
            int q = idx - 512;
            int e = q / 640;
            int rem = q - e * 640;
            int g = rem >> 7, h = rem & 127;
            v = gb[g][e * 128 + h];
        }
        ws[OFF_BIAS + idx] = v;
    }
    if (idx < 2048) {              // zero sync flags every launch (graph-safe)
        reinterpret_cast<int*>(ws + OFF_FLAGS)[idx] = 0;
    }
}

// ---------------- K1: XG[4096][3072] = X[4096][64] @ W_all + bias ----------------
__global__ __launch_bounds__(256) void k1_xproj(
    const float* __restrict__ x, const float* wsr, float* XG)
{
    __shared__ __align__(16) float XT[64 * 68];
    const float* W_all = wsr + OFF_WALL;
    const float* bias  = wsr + OFF_BIAS;
    int bid = blockIdx.x;
    int ct = bid % 48, rt = bid / 48;
    int r0 = rt * 64, c0 = ct * 64;
    for (int p = threadIdx.x; p < 4096; p += 256) {
        int i = p >> 6, k = p & 63;
        XT[k * 68 + i] = x[(r0 + i) * 64 + k];
    }
    __syncthreads();
    int col = c0 + (threadIdx.x & 63);
    int iq = threadIdx.x >> 6;
    float acc[16];
    #pragma unroll
    for (int r = 0; r < 16; r++) acc[r] = 0.f;
    const float* wp = W_all + col;
    #pragma unroll 4
    for (int k = 0; k < 64; k++) {
        float w = wp[k * 3072];
        const float4* xt4 = reinterpret_cast<const float4*>(&XT[k * 68 + iq * 16]);
        #pragma unroll
        for (int r4 = 0; r4 < 4; r4++) {
            float4 xv = xt4[r4];
            acc[r4 * 4 + 0] = fmaf(xv.x, w, acc[r4 * 4 + 0]);
            acc[r4 * 4 + 1] = fmaf(xv.y, w, acc[r4 * 4 + 1]);
            acc[r4 * 4 + 2] = fmaf(xv.z, w, acc[r4 * 4 + 2]);
            acc[r4 * 4 + 3] = fmaf(xv.w, w, acc[r4 * 4 + 3]);
        }
    }
    float bv = bias[col];
    #pragma unroll
    for (int r = 0; r < 16; r++) {
        int row = r0 + iq * 16 + r;
        XG[row * 3072 + col] = acc[r] + bv;
    }
}

// ---------------- K2: recurrence; Whh weights LDS-resident, gate weights reg-resident ----
// 256 blocks x 512 threads. Group of 4 blocks (one per e) = 1 batch pair.
// waL (128 KB) + exchange (~27 KB) = ~155 KB LDS -> hard 1 block/CU, so the
// compiler's own occupancy target allows ~256 VGPR and keeps wg[5][16] live.
// Sync: relaxed agent-scope atomics only (IC-direct), no cache maintenance.
__global__ __launch_bounds__(512, 1) void k2_recur(
    const uint4* __restrict__ WhhH4,    // [e][kq*16+i4][lane] uint4
    const unsigned* __restrict__ WgH,
    const float* __restrict__ XG,
    const float* __restrict__ dt_time,
    const float* __restrict__ alpha,
    float* __restrict__ Gst,
    unsigned* __restrict__ hbuf,
    int* __restrict__ flags,
    float* __restrict__ lam_out)
{
    __shared__ __align__(16) uint4 waL[8192];       // 128 KB: [(kq*16+i4)*128 + lane]
    __shared__ __align__(16) unsigned hL[256][2];   // [pair p=e*64+j/2][slot]
    __shared__ __align__(16) float hsF[2][128];
    __shared__ float pA[4][2][128];
    __shared__ float pB[4][2][5][128];
    __shared__ float red[4];
    const int tid = threadIdx.x;
    const int bid = blockIdx.x;
    const int e   = (bid >> 3) & 3;
    const int grp = (bid & 7) | ((bid >> 5) << 3);
    const int b0  = grp * 2;
    const int kq  = tid >> 7;          // K-quarter
    const int lane = tid & 127;        // output index (col / h')
    const int s = (tid >> 7) & 1, l = lane;   // roles for tid<256

    // --- stage Whh e-slice into LDS (once) ---
    {
        const uint4* src = WhhH4 + (size_t)e * 8192;
        #pragma unroll
        for (int n = 0; n < 16; ++n) waL[tid + 512 * n] = src[tid + 512 * n];
    }
    // --- gate weights into registers (once) ---
    unsigned wg[5][16];
    #pragma unroll
    for (int i = 0; i < 16; i++) {
        #pragma unroll
        for (int g = 0; g < 5; g++)
            wg[g][i] = WgH[(((e * 4 + kq) * 16 + i) * 5 + g) * 128 + lane];
    }
    const float av = alpha[e * 128 + lane];
    int* gflag = flags + grp * 32;
    float cst = 0.f;
    __syncthreads();   // waL ready

    for (int t = 0; t < 32; ++t) {
        const int row0 = t * 128 + b0;
        // (1) prefetch this step's XG slice (issued before the wait)
        float xg0 = 0.f, xgg0 = 0.f, xgg1 = 0.f, xgg2 = 0.f, xgg3 = 0.f, xgg4 = 0.f;
        if (tid < 256) {
            const float* base = XG + (size_t)(row0 + s) * 3072;
            xg0 = base[e * 128 + l];
            const float* gp = base + 512 + e * 640 + l;
            xgg0 = gp[0]; xgg1 = gp[128]; xgg2 = gp[256]; xgg3 = gp[384]; xgg4 = gp[512];
        }
        if (t > 0) {
            // (2) wait for group step t-1 (relaxed poll, no cache maintenance)
            if (tid == 0) {
                while (__hip_atomic_load(&gflag[t - 1], __ATOMIC_RELAXED,
                                         __HIP_MEMORY_SCOPE_AGENT) < 4)
                    __builtin_amdgcn_s_sleep(1);
            }
            __syncthreads();
            asm volatile("" ::: "memory");
            // (3) stage h (parity t&1) -> LDS via IC-direct relaxed atomic loads
            {
                const unsigned* src = hbuf + (size_t)((t & 1) * 64 + grp) * 512;
                unsigned v = __hip_atomic_load(&src[tid], __ATOMIC_RELAXED,
                                               __HIP_MEMORY_SCOPE_AGENT);
                int eh = tid >> 7, sh = (tid >> 6) & 1, p = tid & 63;
                hL[eh * 64 + p][sh] = v;
            }
            __syncthreads();
            // (4) phase A: partial hs dots over K-quarter; wa from LDS (b128 contiguous)
            float a0 = 0.f, a1 = 0.f;
            {
                const uint2* hL2 = reinterpret_cast<const uint2*>(hL);
                #pragma unroll
                for (int i4 = 0; i4 < 16; ++i4) {
                    uint4 w = waL[(kq * 16 + i4) * 128 + lane];
                    uint2 h0 = hL2[kq * 64 + i4 * 4 + 0];
                    uint2 h1 = hL2[kq * 64 + i4 * 4 + 1];
                    uint2 h2 = hL2[kq * 64 + i4 * 4 + 2];
                    uint2 h3 = hL2[kq * 64 + i4 * 4 + 3];
                    a0 = dot2(w.x, h0.x, a0); a1 = dot2(w.x, h0.y, a1);
                    a0 = dot2(w.y, h1.x, a0); a1 = dot2(w.y, h1.y, a1);
                    a0 = dot2(w.z, h2.x, a0); a1 = dot2(w.z, h2.y, a1);
                    a0 = dot2(w.w, h3.x, a0); a1 = dot2(w.w, h3.y, a1);
                }
            }
            pA[kq][0][lane] = a0;
            pA[kq][1][lane] = a1;
            __syncthreads();
            if (tid < 256) {
                float hs = pA[0][s][l] + pA[1][s][l] + pA[2][s][l] + pA[3][s][l] + xg0;
                hsF[s][l] = hs;
            }
        } else {
            if (tid < 256) hsF[s][l] = xg0;   // h=0 at t=0
        }
        __syncthreads();
        // (5) phase B: 5 gate partial dots over K-quarter (K=128); wg in registers
        float b0a = 0.f, b1a = 0.f, b2a = 0.f, b3a = 0.f, b4a = 0.f;
        float b0b = 0.f, b1b = 0.f, b2b = 0.f, b3b = 0.f, b4b = 0.f;
        #pragma unroll
        for (int i = 0; i < 16; i++) {
            float2 f0 = *reinterpret_cast<const float2*>(&hsF[0][kq * 32 + 2 * i]);
            float2 f1 = *reinterpret_cast<const float2*>(&hsF[1][kq * 32 + 2 * i]);
            unsigned h0 = pack2h(f0.x, f0.y);
            unsigned h1 = pack2h(f1.x, f1.y);
            b0a = dot2(wg[0][i], h0, b0a); b0b = dot2(wg[0][i], h1, b0b);
            b1a = dot2(wg[1][i], h0, b1a); b1b = dot2(wg[1][i], h1, b1b);
            b2a = dot2(wg[2][i], h0, b2a); b2b = dot2(wg[2][i], h1, b2b);
            b3a = dot2(wg[3][i], h0, b3a); b3b = dot2(wg[3][i], h1, b3b);
            b4a = dot2(wg[4][i], h0, b4a); b4b = dot2(wg[4][i], h1, b4b);
        }
        pB[kq][0][0][lane] = b0a; pB[kq][0][1][lane] = b1a; pB[kq][0][2][lane] = b2a;
        pB[kq][0][3][lane] = b3a; pB[kq][0][4][lane] = b4a;
        pB[kq][1][0][lane] = b0b; pB[kq][1][1][lane] = b1b; pB[kq][1][2][lane] = b2b;
        pB[kq][1][3][lane] = b3b; pB[kq][1][4][lane] = b4b;
        __syncthreads();
        // (6) cell update + outputs (tid<256: s,l)
        if (tid < 256) {
            float ai = pB[0][s][0][l] + pB[1][s][0][l] + pB[2][s][0][l] + pB[3][s][0][l] + xgg0;
            float af = pB[0][s][1][l] + pB[1][s][1][l] + pB[2][s][1][l] + pB[3][s][1][l] + xgg1;
            float ad = pB[0][s][2][l] + pB[1][s][2][l] + pB[2][s][2][l] + pB[3][s][2][l] + xgg2;
            float ag = pB[0][s][3][l] + pB[1][s][3][l] + pB[2][s][3][l] + pB[3][s][3][l] + xgg3;
            float ao = pB[0][s][4][l] + pB[1][s][4][l] + pB[2][s][4][l] + pB[3][s][4][l] + xgg4;
            float ig = fast_sig(ai);
            float fg = fast_sig(af);
            float dl = __expf(ad);
            float gt = tanhf(ag);
            float og = fast_sig(ao);
            float gc = fmaf(fg, cst, ig * gt);
            float df = cst - gc;
            float dtv = dt_time[row0 + s];
            cst = fmaf(df, __expf(-dl * dtv), gc);
            float hn = og * tanhf(cst);
            size_t go = (size_t)(row0 + s) * 512 + e * 128 + l;
            Gst[0 * GST_PLANE + go] = gc;
            Gst[1 * GST_PLANE + go] = df;
            Gst[2 * GST_PLANE + go] = dl;
            Gst[3 * GST_PLANE + go] = og;
            // pack h_new pairs -> hbuf parity (t+1)&1 via IC-direct atomic store
            float hi = __shfl_down(hn, 1, 64);
            if ((l & 1) == 0) {
                unsigned* dst = hbuf
                    + (size_t)(((t + 1) & 1) * 64 + grp) * 512
                    + (e * 2 + s) * 64 + (l >> 1);
                __hip_atomic_store(dst, pack2h(hn, hi), __ATOMIC_RELAXED,
                                   __HIP_MEMORY_SCOPE_AGENT);
            }
            // lambda reduce
            float lm = av * hn;
            #pragma unroll
            for (int off = 32; off > 0; off >>= 1) lm += __shfl_down(lm, off, 64);
            if ((tid & 63) == 0) red[tid >> 6] = lm;
        }
        __syncthreads();   // drains vmcnt(0): h stores are at IC before flag add
        if (tid == 0) {
            lam_out[(row0 + 0) * 4 + e] = red[0] + red[1];
            lam_out[(row0 + 1) * 4 + e] = red[2] + red[3];
            __hip_atomic_fetch_add(&gflag[t], 1, __ATOMIC_RELAXED,
                                   __HIP_MEMORY_SCOPE_AGENT);
        }
    }
}

// ---------------- K3: trapezoid integrals, 1 block per (t,b) ----------------
__global__ __launch_bounds__(256) void k3_trap(
    const float* __restrict__ Gst, const float* __restrict__ dt_time,
    const float* __restrict__ alpha, float* __restrict__ integ_out)
{
    __shared__ float red[4][2];
    const int row = blockIdx.x;
    const int tid = threadIdx.x;
    const float dtv = dt_time[row];
    const int base = row * 512;
    const int pA = tid, pB = tid + 256;
    float gcA = Gst[0 * GST_PLANE + base + pA];
    float gcB = Gst[0 * GST_PLANE + base + pB];
    float dfA = Gst[1 * GST_PLANE + base + pA];
    float dfB = Gst[1 * GST_PLANE + base + pB];
    float dlA = Gst[2 * GST_PLANE + base + pA];
    float dlB = Gst[2 * GST_PLANE + base + pB];
    float oA  = Gst[3 * GST_PLANE + base + pA];
    float oB  = Gst[3 * GST_PLANE + base + pB];
    float aoA = alpha[pA] * oA;
    float aoB = alpha[pB] * oB;
    float g2A = 2.f * gcA, d2A = 2.f * dfA;
    float g2B = 2.f * gcB, d2B = 2.f * dfB;
    float qA = dlA * dtv, qB = dlB * dtv;
    float rA = __expf(-qA * 0.01f);
    float rB = __expf(-qB * 0.01f);
    float E100A = __expf(-qA);
    float E100B = __expf(-qB);
    float sA = 0.5f * (__fdividef(1.f, __expf(g2A + d2A) + 1.f)
                     + __fdividef(1.f, __expf(fmaf(d2A, E100A, g2A)) + 1.f));
    float sB = 0.5f * (__fdividef(1.f, __expf(g2B + d2B) + 1.f)
                     + __fdividef(1.f, __expf(fmaf(d2B, E100B, g2B)) + 1.f));
    float EA = rA, EB = rB;
    for (int k = 1; k < 100; k++) {
        sA += __fdividef(1.f, __expf(fmaf(d2A, EA, g2A)) + 1.f);
        sB += __fdividef(1.f, __expf(fmaf(d2B, EB, g2B)) + 1.f);
        EA *= rA;
        EB *= rB;
    }
    float vA = aoA * (100.f - 2.f * sA);
    float vB = aoB * (100.f - 2.f * sB);
    #pragma unroll
    for (int off = 32; off > 0; off >>= 1) {
        vA += __shfl_down(vA, off, 64);
        vB += __shfl_down(vB, off, 64);
    }
    const int wv = tid >> 6;
    if ((tid & 63) == 0) { red[wv][0] = vA; red[wv][1] = vB; }
    __syncthreads();
    if (tid < 4) {
        float v = (tid < 2) ? (red[2 * tid][0] + red[2 * tid + 1][0])
                            : (red[2 * (tid - 2)][1] + red[2 * (tid - 2) + 1][1]);
        integ_out[row * 4 + tid] = v * (dtv * 0.01f);
    }
}

extern "C" void kernel_launch(void* const* d_in, const int* in_sizes, int n_in,
                              void* d_out, int out_size, void* d_ws, size_t ws_size,
                              hipStream_t stream)
{
    const float* x_time  = (const float*)d_in[0];
    const float* dt_time = (const float*)d_in[1];
    const float* Wh_w = (const float*)d_in[2];
    const float* Wh_b = (const float*)d_in[3];
    const float* Wi_w = (const float*)d_in[4];
    const float* Wi_b = (const float*)d_in[5];
    const float* Wf_w = (const float*)d_in[6];
    const float* Wf_b = (const float*)d_in[7];
    const float* Wd_w = (const float*)d_in[8];
    const float* Wd_b = (const float*)d_in[9];
    const float* Wg_w = (const float*)d_in[10];
    const float* Wg_b = (const float*)d_in[11];
    const float* Wo_w = (const float*)d_in[12];
    const float* Wo_b = (const float*)d_in[13];
    const float* alpha = (const float*)d_in[14];

    float* ws = (float*)d_ws;
    float* XG   = ws + OFF_XG;
    float* Gst  = ws + OFF_GST;
    unsigned* hbuf = (unsigned*)(ws + OFF_HBUF);
    int*   flags = (int*)(ws + OFF_FLAGS);
    float* lam_out   = (float*)d_out;
    float* integ_out = lam_out + 32 * 128 * 4;

    k0_pack<<<3072, 256, 0, stream>>>(Wh_w, Wh_b, Wi_w, Wi_b, Wf_w, Wf_b,
                                      Wd_w, Wd_b, Wg_w, Wg_b, Wo_w, Wo_b, ws);
    k1_xproj<<<3072, 256, 0, stream>>>(x_time, ws, XG);
    k2_recur<<<256, 512, 0, stream>>>(
        (const uint4*)(ws + OFF_WHHH), (const unsigned*)(ws + OFF_WGH),
        XG, dt_time, alpha, Gst, hbuf, flags, lam_out);
    k3_trap<<<4096, 256, 0, stream>>>(Gst, dt_time, alpha, integ_out);
}